// Round 14
// baseline (2578.341 us; speedup 1.0000x reference)
//
#include <hip/hip_runtime.h>

typedef unsigned int u32;
typedef unsigned short u16;
typedef _Float16 f16;
typedef f16 f16x8 __attribute__((ext_vector_type(8)));
typedef float f32x4 __attribute__((ext_vector_type(4)));
typedef u16 u16x8 __attribute__((ext_vector_type(8)));

#define DIM 1024
#define BATCH 32768
#define RANK 32
#define NLIN 18

__device__ __forceinline__ u16 f2h(float f) {
    f16 h = (f16)f;
    return *(u16*)&h;
}
__device__ __forceinline__ float h2f(u16 u) {
    f16 h;
    *(u16*)&h = u;
    return (float)h;
}

__device__ __forceinline__ void gload16(const u16* g, u16* l) {
    __builtin_amdgcn_global_load_lds((__attribute__((address_space(1))) const void*)g,
                                     (__attribute__((address_space(3))) void*)l,
                                     16, 0, 0);
}

#define BAR()        __builtin_amdgcn_s_barrier()
#define SB0()        __builtin_amdgcn_sched_barrier(0)
#define ASM_VM0()    asm volatile("s_waitcnt vmcnt(0)" ::: "memory")
#define ASM_VM4()    asm volatile("s_waitcnt vmcnt(4)" ::: "memory")
#define ASM_LG0()    asm volatile("s_waitcnt lgkmcnt(0)" ::: "memory")

// ---- W_eff = dequant(wq, scales) + lb @ la  -> fp16 [NLIN][DIM][DIM] ----
__global__ __launch_bounds__(256) void build_weff(
    const int* __restrict__ wq, const float* __restrict__ scales,
    const float* __restrict__ la, const float* __restrict__ lb,
    u16* __restrict__ weff)
{
    const int rb = blockIdx.x;   // 0..63, 16 rows each
    const int li = blockIdx.y;   // 0..17
    const int tid = threadIdx.x;
    const int row0 = rb * 16;
    const int* wqL = wq + (size_t)li * DIM * DIM;
    const float* sL = scales + (size_t)li * (DIM * DIM / 16);
    const float* laL = la + (size_t)li * RANK * DIM;
    const float* lbL = lb + (size_t)li * DIM * RANK;
    u16* wout = weff + (size_t)li * DIM * DIM;

    for (int kc = 0; kc < 4; ++kc) {
        const int k = kc * 256 + tid;
        float lar[RANK];
        #pragma unroll
        for (int r = 0; r < RANK; ++r) lar[r] = laL[r * DIM + k];
        const int ks = k >> 4;
        #pragma unroll
        for (int og = 0; og < 16; og += 4) {
            const int m0 = row0 + og;
            float a0 = ((float)wqL[(m0 + 0) * DIM + k] - 8.0f) * sL[((m0 + 0) << 6) + ks];
            float a1 = ((float)wqL[(m0 + 1) * DIM + k] - 8.0f) * sL[((m0 + 1) << 6) + ks];
            float a2 = ((float)wqL[(m0 + 2) * DIM + k] - 8.0f) * sL[((m0 + 2) << 6) + ks];
            float a3 = ((float)wqL[(m0 + 3) * DIM + k] - 8.0f) * sL[((m0 + 3) << 6) + ks];
            #pragma unroll
            for (int r = 0; r < RANK; ++r) {
                const float lv = lar[r];
                a0 += lbL[(m0 + 0) * RANK + r] * lv;
                a1 += lbL[(m0 + 1) * RANK + r] * lv;
                a2 += lbL[(m0 + 2) * RANK + r] * lv;
                a3 += lbL[(m0 + 3) * RANK + r] * lv;
            }
            wout[(m0 + 0) * DIM + k] = f2h(a0);
            wout[(m0 + 1) * DIM + k] = f2h(a1);
            wout[(m0 + 2) * DIM + k] = f2h(a2);
            wout[(m0 + 3) * DIM + k] = f2h(a3);
        }
    }
}

// ---- x fp32 -> fp16 ----
__global__ __launch_bounds__(256) void xcast(const float* __restrict__ x, u16* __restrict__ o) {
    size_t i = ((size_t)blockIdx.x * 256 + threadIdx.x) * 8;
    float4 a = *(const float4*)(x + i);
    float4 b = *(const float4*)(x + i + 4);
    u16x8 v;
    v[0] = f2h(a.x); v[1] = f2h(a.y); v[2] = f2h(a.z); v[3] = f2h(a.w);
    v[4] = f2h(b.x); v[5] = f2h(b.y); v[6] = f2h(b.z); v[7] = f2h(b.w);
    *(u16x8*)(o + i) = v;
}

// ---- 128x128x(BK=32) GEMM, 4 waves (2Mx2N, wave 64x64), TLP-first design:
// acc only 64 regs/thread -> ~3 waves/SIMD -> 3 BLOCKS co-resident per CU
// (12 waves), so barrier/waitcnt stalls of one block hide under the other
// blocks' MFMAs (the 2-waves/SIMD lockstep was the r1-r13 structural limit).
// K-major LDS layout [kg][row][8] (kg = 8-elem K-chunk): gload_lds staging is
// linear AND frag ds_read_b128 is conflict-free by construction (no swizzle).
// A,B each TRIPLE-buffered (8 KiB/buf): stage tile t+2 into buf[(t+2)%3]
// (holds t-1, drained by all waves' lgkm0 in iter t-1, certified by BAR1);
// one vmcnt(4) per tile retires t+1 (leaves t+2's 4 in flight); BAR2
// publishes. Frag reads for t+1 issued after the consuming QUADs (WAR via
// register dependence). 2 barriers + 16 MFMA + 8 ds_read per tile, 32 tiles.
// LDS = 48 KiB -> 3 blocks/CU. Epilogue: r13 transpose + 2-deep res prefetch.
// EPI: 0 = relu(acc+bias)->fp16 ; 1 = acc+bias+res->fp16 ; 2 = acc+bias+res->fp32
template<int EPI>
__global__ __launch_bounds__(256, 3) void gemm128(
    const u16* __restrict__ X, const u16* __restrict__ W,
    const float* __restrict__ bias, const u16* __restrict__ res,
    void* __restrict__ outp)
{
    __shared__ __align__(16) u16 As3[3 * 4096];   // [buf][kg][row][8] u16
    __shared__ __align__(16) u16 Bs3[3 * 4096];
    const int tid = threadIdx.x;
    const int bid = blockIdx.x;
    // XCD-bijective swizzle: 2048 blocks, 8 XCDs, 256 contiguous wg per XCD
    const int wg = (bid & 7) * 256 + (bid >> 3);
    const int bm = wg >> 3;        // 0..255
    const int bn = wg & 7;         // 0..7
    const int wid = tid >> 6;
    const int lane = tid & 63;
    const int wm = wid >> 1;       // 0..1
    const int wn = wid & 1;        // 0..1

    // ---- staging: thread handles chunks tid and tid+256 (c = kg*128+row) ----
    const int srow = tid & 127;
    const int skg = tid >> 7;                     // 0..1 (chunk2 adds kg+2)
    const u16* gA = X + (size_t)(bm * 128 + srow) * DIM + skg * 8;
    const u16* gB = W + (size_t)(bn * 128 + srow) * DIM + skg * 8;
    const int d1 = tid * 8;                       // u16 LDS offset, chunk1
    // chunk2 dest = d1 + 2048 (kg+2 region)

    // ---- fragment read bases (u16 offsets within a buffer) ----
    const int kg = lane >> 4;                     // 0..3
    const int r16 = lane & 15;
    const int aBase = kg * 1024 + (wm * 64 + r16) * 8;
    const int bBase = kg * 1024 + (wn * 64 + r16) * 8;

    f32x4 acc[4][4];
    #pragma unroll
    for (int i = 0; i < 4; ++i)
        #pragma unroll
        for (int j = 0; j < 4; ++j)
            acc[i][j] = (f32x4){0.f, 0.f, 0.f, 0.f};
    f16x8 af[4], bf[4];

    #define STAGE(KT, OFF) { \
        const u16* ga_ = gA + (KT) * 32; \
        const u16* gb_ = gB + (KT) * 32; \
        gload16(ga_,      &As3[(OFF) + d1]); \
        gload16(ga_ + 16, &As3[(OFF) + d1 + 2048]); \
        gload16(gb_,      &Bs3[(OFF) + d1]); \
        gload16(gb_ + 16, &Bs3[(OFF) + d1 + 2048]); }
    #define RD_FRAGS(OFF) { \
        _Pragma("unroll") \
        for (int f = 0; f < 4; ++f) { \
            af[f] = *(const f16x8*)&As3[(OFF) + aBase + f * 128]; \
            bf[f] = *(const f16x8*)&Bs3[(OFF) + bBase + f * 128]; \
        } }
    #define QUADS() { \
        __builtin_amdgcn_s_setprio(1); \
        _Pragma("unroll") \
        for (int m = 0; m < 4; ++m) \
            _Pragma("unroll") \
            for (int n = 0; n < 4; ++n) \
                acc[m][n] = __builtin_amdgcn_mfma_f32_16x16x32_f16( \
                    af[m], bf[n], acc[m][n], 0, 0, 0); \
        __builtin_amdgcn_s_setprio(0); }

    // ---- prologue: stage t0 -> buf0, t1 -> buf1 ----
    STAGE(0, 0);
    STAGE(1, 4096);
    ASM_VM4();       // t0's 4 loads landed (t1's 4 stay in flight)
    BAR();
    RD_FRAGS(0);     // tile-0 fragments
    SB0();

    int oCur = 0, oNext = 4096, oWr = 8192;
    #pragma unroll 1
    for (int t = 0; t < 32; ++t) {
        BAR();                               // BAR1: all waves past t-1 lgkm0
        if (t <= 29) STAGE(t + 2, oWr);      // buf holds t-1: drained (BAR1)
        if (t <= 29) ASM_VM4();              // retire t+1's 4; leave t+2's 4
        else if (t == 30) ASM_VM0();
        BAR();                               // BAR2: t+1 staging published
        ASM_LG0(); SB0();                    // frag reads (issued last iter) done
        QUADS();                             // 16 MFMA on tile t
        if (t <= 30) RD_FRAGS(oNext);        // t+1 frags, AFTER consumers (WAR ok)
        SB0();
        int tmp = oCur; oCur = oNext; oNext = oWr; oWr = tmp;
    }

    // ---- epilogue: per-wave LDS transpose -> vector stores; res 2-deep ----
    ASM_LG0();       // own reads drained
    BAR();           // all waves' reads drained -> LDS reusable
    float* blk = (float*)&As3[0] + wid * 1088;   // [16][68] f32 per wave
    const int mrow = bm * 128 + wm * 64;
    const int ncol = bn * 128 + wn * 64 + (lane & 7) * 8;
    float4 bv0 = *(const float4*)&bias[ncol];
    float4 bv1 = *(const float4*)&bias[ncol + 4];
    u16x8 rvp[2][2];   // res prefetch [parity][pass]
    if (EPI != 0) {
        #pragma unroll
        for (int pass = 0; pass < 2; ++pass) {
            const int m = mrow + pass * 8 + (lane >> 3);
            rvp[0][pass] = *(const u16x8*)(res + (size_t)m * DIM + ncol);
        }
    }
    #pragma unroll
    for (int fm = 0; fm < 4; ++fm) {
        if (EPI != 0 && fm < 3) {   // issue fm+1's res loads (consumed next iter)
            #pragma unroll
            for (int pass = 0; pass < 2; ++pass) {
                const int m = mrow + (fm + 1) * 16 + pass * 8 + (lane >> 3);
                rvp[(fm + 1) & 1][pass] = *(const u16x8*)(res + (size_t)m * DIM + ncol);
            }
        }
        __builtin_amdgcn_sched_barrier(0);
        #pragma unroll
        for (int fn = 0; fn < 4; ++fn)
            #pragma unroll
            for (int reg = 0; reg < 4; ++reg)
                blk[((lane >> 4) * 4 + reg) * 68 + (lane & 15) + fn * 16] = acc[fm][fn][reg];
        ASM_LG0();
        __builtin_amdgcn_sched_barrier(0);
        #pragma unroll
        for (int pass = 0; pass < 2; ++pass) {
            const float* rp = &blk[(pass * 8 + (lane >> 3)) * 68 + (lane & 7) * 8];
            float4 v0 = *(const float4*)rp;
            float4 v1 = *(const float4*)(rp + 4);
            v0.x += bv0.x; v0.y += bv0.y; v0.z += bv0.z; v0.w += bv0.w;
            v1.x += bv1.x; v1.y += bv1.y; v1.z += bv1.z; v1.w += bv1.w;
            const int m = mrow + fm * 16 + pass * 8 + (lane >> 3);
            const size_t gi = (size_t)m * DIM + ncol;
            if (EPI == 0) {
                u16x8 o;
                o[0] = f2h(fmaxf(v0.x, 0.f)); o[1] = f2h(fmaxf(v0.y, 0.f));
                o[2] = f2h(fmaxf(v0.z, 0.f)); o[3] = f2h(fmaxf(v0.w, 0.f));
                o[4] = f2h(fmaxf(v1.x, 0.f)); o[5] = f2h(fmaxf(v1.y, 0.f));
                o[6] = f2h(fmaxf(v1.z, 0.f)); o[7] = f2h(fmaxf(v1.w, 0.f));
                *(u16x8*)((u16*)outp + gi) = o;
            } else {
                u16x8 rv = rvp[fm & 1][pass];
                v0.x += h2f(rv[0]); v0.y += h2f(rv[1]); v0.z += h2f(rv[2]); v0.w += h2f(rv[3]);
                v1.x += h2f(rv[4]); v1.y += h2f(rv[5]); v1.z += h2f(rv[6]); v1.w += h2f(rv[7]);
                if (EPI == 1) {
                    u16x8 o;
                    o[0] = f2h(v0.x); o[1] = f2h(v0.y); o[2] = f2h(v0.z); o[3] = f2h(v0.w);
                    o[4] = f2h(v1.x); o[5] = f2h(v1.y); o[6] = f2h(v1.z); o[7] = f2h(v1.w);
                    *(u16x8*)((u16*)outp + gi) = o;
                } else {
                    *(float4*)((float*)outp + gi) = v0;
                    *(float4*)((float*)outp + gi + 4) = v1;
                }
            }
        }
        ASM_LG0();
    }
    #undef STAGE
    #undef RD_FRAGS
    #undef QUADS
}

// ---- LayerNorm: fp16 in -> fp16 out, one wave per row ----
__global__ __launch_bounds__(256) void ln_k(const u16* __restrict__ in,
    const float* __restrict__ g, const float* __restrict__ b, u16* __restrict__ out)
{
    int row = blockIdx.x * 4 + (threadIdx.x >> 6);
    int lane = threadIdx.x & 63;
    const u16* rp = in + (size_t)row * DIM;
    u16x8 v0 = *(const u16x8*)(rp + lane * 8);
    u16x8 v1 = *(const u16x8*)(rp + 512 + lane * 8);
    float f[16];
    #pragma unroll
    for (int j = 0; j < 8; ++j) { f[j] = h2f(v0[j]); f[8 + j] = h2f(v1[j]); }
    float s = 0.f, sq = 0.f;
    #pragma unroll
    for (int j = 0; j < 16; ++j) { s += f[j]; sq += f[j] * f[j]; }
    #pragma unroll
    for (int m = 1; m < 64; m <<= 1) { s += __shfl_xor(s, m); sq += __shfl_xor(sq, m); }
    float mean = s * (1.0f / 1024.0f);
    float var = sq * (1.0f / 1024.0f) - mean * mean;
    float rstd = 1.0f / sqrtf(var + 1e-5f);
    u16x8 o0, o1;
    #pragma unroll
    for (int j = 0; j < 8; ++j) {
        int c0 = lane * 8 + j, c1 = 512 + lane * 8 + j;
        o0[j] = f2h((f[j] - mean) * rstd * g[c0] + b[c0]);
        o1[j] = f2h((f[8 + j] - mean) * rstd * g[c1] + b[c1]);
    }
    u16* op = out + (size_t)row * DIM;
    *(u16x8*)(op + lane * 8) = o0;
    *(u16x8*)(op + 512 + lane * 8) = o1;
}

extern "C" void kernel_launch(void* const* d_in, const int* in_sizes, int n_in,
                              void* d_out, int out_size, void* d_ws, size_t ws_size,
                              hipStream_t stream) {
    const float* x      = (const float*)d_in[0];
    const int*   wq     = (const int*)d_in[1];
    const float* scales = (const float*)d_in[2];
    const float* bias   = (const float*)d_in[3];
    const float* la     = (const float*)d_in[4];
    const float* lb     = (const float*)d_in[5];
    const float* gamma  = (const float*)d_in[6];
    const float* beta   = (const float*)d_in[7];

    char* ws = (char*)d_ws;
    u16* Weff = (u16*)ws;                                      // 37,748,736 B
    u16* actA = (u16*)(ws + (size_t)NLIN * DIM * DIM * 2);     // 67,108,864 B
    u16* actB = actA + (size_t)BATCH * DIM;                    // 67,108,864 B
    u16* dob  = (u16*)d_out;   // d_out doubles as fp16 scratch (134 MB total)
    float* dof = (float*)d_out;

    build_weff<<<dim3(64, 18), 256, 0, stream>>>(wq, scales, la, lb, Weff);
    xcast<<<(BATCH * DIM) / 2048, 256, 0, stream>>>(x, actA);

    int li = 0;
    for (int blk = 0; blk < 6; ++blk) {
        const u16* w0 = Weff + (size_t)(li + 0) * DIM * DIM;
        const u16* w1 = Weff + (size_t)(li + 1) * DIM * DIM;
        const u16* w2 = Weff + (size_t)(li + 2) * DIM * DIM;
        const float* b0 = bias + (li + 0) * DIM;
        const float* b1 = bias + (li + 1) * DIM;
        const float* b2 = bias + (li + 2) * DIM;
        if (blk < 5) {
            // X(actA) -> h1(actB) -> h2(d_out fp16) -> h3(actB) -> LN -> actA
            gemm128<0><<<2048, 256, 0, stream>>>(actA, w0, b0, nullptr, actB);
            gemm128<0><<<2048, 256, 0, stream>>>(actB, w1, b1, nullptr, dob);
            gemm128<1><<<2048, 256, 0, stream>>>(dob,  w2, b2, actA, actB);
            ln_k<<<BATCH / 4, 256, 0, stream>>>(actB, gamma + blk * DIM, beta + blk * DIM, actA);
        } else {
            // final block: keep d_out free of live reads at the fp32 write
            gemm128<0><<<2048, 256, 0, stream>>>(actA, w0, b0, nullptr, dob);
            gemm128<0><<<2048, 256, 0, stream>>>(dob,  w1, b1, nullptr, actB);
            gemm128<2><<<2048, 256, 0, stream>>>(actB, w2, b2, actA, (void*)dof);
        }
        li += 3;
    }
}